// Round 1
// baseline (2124.022 us; speedup 1.0000x reference)
//
#include <hip/hip_runtime.h>

// -------------------- init: deg=1, zero accumulators --------------------
__global__ void k_init(float* __restrict__ deg, float* __restrict__ a1,
                       float* __restrict__ a2, int n, int n64) {
    int i = blockIdx.x * blockDim.x + threadIdx.x;
    if (i < n) deg[i] = 1.0f;          // self-loop contributes 1 to degree
    if (i < n64) { a1[i] = 0.0f; a2[i] = 0.0f; }
}

// -------------------- degree count over col --------------------
__global__ void k_deg_count(const int* __restrict__ col, float* __restrict__ deg, int e) {
    int i = blockIdx.x * blockDim.x + threadIdx.x;
    if (i < e) atomicAdd(&deg[col[i]], 1.0f);
}

__global__ void k_rsqrt(float* __restrict__ deg, int n) {
    int i = blockIdx.x * blockDim.x + threadIdx.x;
    if (i < n) deg[i] = rsqrtf(deg[i]);   // deg >= 1 always (self-loop)
}

// -------------------- small GEMM: out[n][OUT] = in[n][K] @ W[K][OUT] --------------------
// Block: 256 threads, processes NPB = 1024/OUT nodes; 4 outputs per thread.
template<int K, int OUT, bool BIAS, bool RELU>
__launch_bounds__(256)
__global__ void k_gemm(const float* __restrict__ in, const float* __restrict__ W,
                       const float* __restrict__ b, float* __restrict__ out, int n) {
    constexpr int NPB = 1024 / OUT;        // 16 (OUT=64) or 8 (OUT=128)
    constexpr int GS  = 256 / OUT;         // node-group stride: 4 or 2
    __shared__ float sW[K * OUT];
    __shared__ float sX[NPB][K + 1];       // +1 pad against bank conflicts

    const int tid  = threadIdx.x;
    const int base = blockIdx.x * NPB;

    for (int i = tid; i < K * OUT; i += 256) sW[i] = W[i];
    for (int i = tid; i < NPB * K; i += 256) {
        int m = i / K, k = i - m * K;
        int node = base + m;
        sX[m][k] = (node < n) ? in[(long)node * K + k] : 0.0f;
    }
    __syncthreads();

    const int ch = tid % OUT;
    const int g  = tid / OUT;

    float acc[4] = {0.f, 0.f, 0.f, 0.f};
    #pragma unroll 4
    for (int k = 0; k < K; ++k) {
        float w = sW[k * OUT + ch];
        #pragma unroll
        for (int j = 0; j < 4; ++j)
            acc[j] += sX[g + j * GS][k] * w;
    }

    #pragma unroll
    for (int j = 0; j < 4; ++j) {
        int node = base + g + j * GS;
        if (node < n) {
            float v = acc[j];
            if (BIAS) v += b[ch];
            if (RELU) v = fmaxf(v, 0.0f);
            out[(long)node * OUT + ch] = v;
        }
    }
}

// -------------------- edge scatter: acc[col] += h[row] * dinv[row]*dinv[col] --------------------
// one 64-lane wave per edge, lane = channel
__global__ void k_scatter(const int* __restrict__ row, const int* __restrict__ col,
                          const float* __restrict__ dinv, const float* __restrict__ h,
                          float* __restrict__ acc, int e) {
    int t = blockIdx.x * blockDim.x + threadIdx.x;
    int lane = t & 63;
    int eidx = t >> 6;
    if (eidx >= e) return;
    int r = row[eidx], c = col[eidx];
    float nrm = dinv[r] * dinv[c];
    float v = h[(long)r * 64 + lane] * nrm;
    atomicAdd(&acc[(long)c * 64 + lane], v);
}

// -------------------- conv epilogue: acc = relu(acc + h*dinv^2 + b) --------------------
__global__ void k_conv_epilogue(const float* __restrict__ h, const float* __restrict__ dinv,
                                const float* __restrict__ b, float* __restrict__ acc, int n) {
    int i = blockIdx.x * blockDim.x + threadIdx.x;
    if (i >= n * 64) return;
    int node = i >> 6, ch = i & 63;
    float d = dinv[node];
    float v = acc[i] + h[i] * d * d + b[ch];
    acc[i] = fmaxf(v, 0.0f);
}

// -------------------- edge scores: out[e] = dot(nr[row[e]], nr[col[e]]) --------------------
// 16 lanes per edge, float4 loads, shuffle reduce within the 16-group
__global__ void k_edge_scores(const int* __restrict__ row, const int* __restrict__ col,
                              const float* __restrict__ nr, float* __restrict__ out, int e) {
    int t = blockIdx.x * blockDim.x + threadIdx.x;
    int sub  = t & 15;
    int eidx = t >> 4;
    if (eidx >= e) return;
    int r = row[eidx], c = col[eidx];
    float4 a  = *reinterpret_cast<const float4*>(&nr[(long)r * 64 + sub * 4]);
    float4 bb = *reinterpret_cast<const float4*>(&nr[(long)c * 64 + sub * 4]);
    float s = a.x * bb.x + a.y * bb.y + a.z * bb.z + a.w * bb.w;
    s += __shfl_xor(s, 1);
    s += __shfl_xor(s, 2);
    s += __shfl_xor(s, 4);
    s += __shfl_xor(s, 8);
    if (sub == 0) out[eidx] = s;
}

extern "C" void kernel_launch(void* const* d_in, const int* in_sizes, int n_in,
                              void* d_out, int out_size, void* d_ws, size_t ws_size,
                              hipStream_t stream) {
    const float* x   = (const float*)d_in[0];
    const int*   ei  = (const int*)d_in[1];
    const float* W1  = (const float*)d_in[2];
    const float* b1  = (const float*)d_in[3];
    const float* W2  = (const float*)d_in[4];
    const float* b2  = (const float*)d_in[5];
    const float* Wd1 = (const float*)d_in[6];
    const float* bd1 = (const float*)d_in[7];
    const float* Wd2 = (const float*)d_in[8];
    const float* bd2 = (const float*)d_in[9];

    const int N = in_sizes[0] / 128;
    const int E = in_sizes[1] / 2;
    const int* row = ei;
    const int* col = ei + E;

    // d_out layout: recon_x [N*128] | edge_scores [E] | node_repr [N*64]
    float* recon_out  = (float*)d_out;
    float* escore_out = recon_out + (long)N * 128;
    float* nr_out     = escore_out + E;

    // workspace layout (floats): dinv [N] | buf1 [N*64] | buf2 [N*64]
    float* dinv = (float*)d_ws;
    float* buf1 = dinv + N;
    float* buf2 = buf1 + (long)N * 64;

    const int n64 = N * 64;

    // 1. init deg=1, zero accumulators (buf2 = layer1 acc, nr_out = layer2 acc)
    k_init<<<(n64 + 255) / 256, 256, 0, stream>>>(dinv, buf2, nr_out, N, n64);
    // 2. degree count
    k_deg_count<<<(E + 255) / 256, 256, 0, stream>>>(col, dinv, E);
    // 3. dinv = rsqrt(deg)
    k_rsqrt<<<(N + 255) / 256, 256, 0, stream>>>(dinv, N);
    // 4. buf1 = x @ W1
    k_gemm<128, 64, false, false><<<(N + 15) / 16, 256, 0, stream>>>(x, W1, nullptr, buf1, N);
    // 5. scatter layer 1: buf2[col] += buf1[row]*norm
    k_scatter<<<(E * 64 + 255) / 256, 256, 0, stream>>>(row, col, dinv, buf1, buf2, E);
    // 6. buf2 = relu(buf2 + buf1*dinv^2 + b1)   (self loop + bias + relu)
    k_conv_epilogue<<<(n64 + 255) / 256, 256, 0, stream>>>(buf1, dinv, b1, buf2, N);
    // 7. buf1 = buf2 @ W2
    k_gemm<64, 64, false, false><<<(N + 15) / 16, 256, 0, stream>>>(buf2, W2, nullptr, buf1, N);
    // 8. scatter layer 2 into nr_out
    k_scatter<<<(E * 64 + 255) / 256, 256, 0, stream>>>(row, col, dinv, buf1, nr_out, E);
    // 9. nr = relu(nr + buf1*dinv^2 + b2)
    k_conv_epilogue<<<(n64 + 255) / 256, 256, 0, stream>>>(buf1, dinv, b2, nr_out, N);
    // 10. buf2 = relu(nr @ Wd1 + bd1)
    k_gemm<64, 64, true, true><<<(N + 15) / 16, 256, 0, stream>>>(nr_out, Wd1, bd1, buf2, N);
    // 11. recon = buf2 @ Wd2 + bd2
    k_gemm<64, 128, true, false><<<(N + 7) / 8, 256, 0, stream>>>(buf2, Wd2, bd2, recon_out, N);
    // 12. edge scores
    k_edge_scores<<<((long)E * 16 + 255) / 256, 256, 0, stream>>>(row, col, nr_out, escore_out, E);
}

// Round 2
// 1149.389 us; speedup vs baseline: 1.8480x; 1.8480x over previous
//
#include <hip/hip_runtime.h>

// ==================== utility ====================
__global__ void k_zero_i(int* __restrict__ p, int n) {
    int i = blockIdx.x * blockDim.x + threadIdx.x;
    if (i < n) p[i] = 0;
}
__global__ void k_zero_f(float* __restrict__ p, long n) {
    long i = blockIdx.x * (long)blockDim.x + threadIdx.x;
    if (i < n) p[i] = 0.0f;
}

// ==================== degree / dinv ====================
__global__ void k_deg_count(const int* __restrict__ col, int* __restrict__ cnt, int e) {
    int i = blockIdx.x * blockDim.x + threadIdx.x;
    if (i < e) atomicAdd(&cnt[col[i]], 1);
}
__global__ void k_dinv(const int* __restrict__ cnt, float* __restrict__ dinv, int n) {
    int i = blockIdx.x * blockDim.x + threadIdx.x;
    if (i < n) dinv[i] = rsqrtf((float)cnt[i] + 1.0f);  // +1 self-loop
}

// ==================== exclusive scan (3-kernel, 1024 elems/block) ====================
__global__ void k_scan1(const int* __restrict__ cnt, int* __restrict__ start,
                        int* __restrict__ bsum, int n) {
    __shared__ int ts[256];
    const int tid = threadIdx.x;
    const int base = blockIdx.x * 1024 + tid * 4;
    int v[4], tot = 0;
    #pragma unroll
    for (int k = 0; k < 4; ++k) {
        int idx = base + k;
        v[k] = (idx < n) ? cnt[idx] : 0;
        tot += v[k];
    }
    ts[tid] = tot;
    __syncthreads();
    for (int off = 1; off < 256; off <<= 1) {
        int add = (tid >= off) ? ts[tid - off] : 0;
        __syncthreads();
        ts[tid] += add;
        __syncthreads();
    }
    int excl = ts[tid] - tot;  // exclusive prefix of this thread within block
    int run = excl;
    #pragma unroll
    for (int k = 0; k < 4; ++k) {
        int idx = base + k;
        if (idx < n) start[idx] = run;
        run += v[k];
    }
    if (tid == 255) bsum[blockIdx.x] = ts[255];
}
__global__ void k_scan2(int* __restrict__ bsum, int nb) {
    if (threadIdx.x == 0 && blockIdx.x == 0) {
        int acc = 0;
        for (int i = 0; i < nb; ++i) { int t = bsum[i]; bsum[i] = acc; acc += t; }
    }
}
__global__ void k_scan3(int* __restrict__ start, const int* __restrict__ bsum,
                        int* __restrict__ cursor, int n, int e) {
    int i = blockIdx.x * blockDim.x + threadIdx.x;
    if (i < n) {
        int s = start[i] + bsum[i >> 10];
        start[i] = s;
        cursor[i] = s;
    }
    if (i == 0) start[n] = e;
}

// ==================== CSR bucket fill ====================
__global__ void k_fill(const int* __restrict__ row, const int* __restrict__ col,
                       int* __restrict__ cursor, int* __restrict__ srow,
                       int* __restrict__ eid, int e) {
    int i = blockIdx.x * blockDim.x + threadIdx.x;
    if (i < e) {
        int c = col[i];
        int p = atomicAdd(&cursor[c], 1);
        srow[p] = row[i];
        eid[p] = i;
    }
}

// ==================== small GEMM: out[n][OUT] = in[n][K] @ W[K][OUT] ====================
// optional epilogue: bias, relu, per-node scale (hs = h * dinv[node])
template<int K, int OUT, bool BIAS, bool RELU, bool SCALE>
__launch_bounds__(256)
__global__ void k_gemm(const float* __restrict__ in, const float* __restrict__ W,
                       const float* __restrict__ b, const float* __restrict__ scale,
                       float* __restrict__ out, int n) {
    constexpr int NPB = 1024 / OUT;        // nodes per block: 16 (OUT=64) or 8 (OUT=128)
    constexpr int GS  = 256 / OUT;         // node-group stride: 4 or 2
    __shared__ float sW[K * OUT];
    __shared__ float sX[NPB][K + 1];

    const int tid  = threadIdx.x;
    const int base = blockIdx.x * NPB;

    for (int i = tid; i < K * OUT; i += 256) sW[i] = W[i];
    for (int i = tid; i < NPB * K; i += 256) {
        int m = i / K, k = i - m * K;
        int node = base + m;
        sX[m][k] = (node < n) ? in[(long)node * K + k] : 0.0f;
    }
    __syncthreads();

    const int ch = tid % OUT;
    const int g  = tid / OUT;

    float acc[4] = {0.f, 0.f, 0.f, 0.f};
    #pragma unroll 4
    for (int k = 0; k < K; ++k) {
        float w = sW[k * OUT + ch];
        #pragma unroll
        for (int j = 0; j < 4; ++j)
            acc[j] += sX[g + j * GS][k] * w;
    }

    #pragma unroll
    for (int j = 0; j < 4; ++j) {
        int node = base + g + j * GS;
        if (node < n) {
            float v = acc[j];
            if (BIAS) v += b[ch];
            if (RELU) v = fmaxf(v, 0.0f);
            if (SCALE) v *= scale[node];
            out[(long)node * OUT + ch] = v;
        }
    }
}

// ==================== gather-reduce conv (no atomics) ====================
// out[c] = relu(dinv[c] * (sum_{r in N(c)} hs[r] + hs[c]) + b)   where hs = h*dinv
__global__ void k_gather_conv(const int* __restrict__ start, const int* __restrict__ srow,
                              const float* __restrict__ hs, const float* __restrict__ dinv,
                              const float* __restrict__ b, float* __restrict__ out, int n) {
    int node = blockIdx.x * 4 + (threadIdx.x >> 6);
    if (node >= n) return;
    int lane = threadIdx.x & 63;
    int s = start[node], e2 = start[node + 1];
    float acc = hs[(long)node * 64 + lane];   // self-loop (already dinv-scaled)
    for (int base = s; base < e2; base += 64) {
        int rem = e2 - base;
        int m = rem < 64 ? rem : 64;
        int rj = (lane < m) ? srow[base + lane] : 0;
        int j = 0;
        for (; j + 4 <= m; j += 4) {
            int r0 = __shfl(rj, j);
            int r1 = __shfl(rj, j + 1);
            int r2 = __shfl(rj, j + 2);
            int r3 = __shfl(rj, j + 3);
            float a0 = hs[(long)r0 * 64 + lane];
            float a1 = hs[(long)r1 * 64 + lane];
            float a2 = hs[(long)r2 * 64 + lane];
            float a3 = hs[(long)r3 * 64 + lane];
            acc += a0; acc += a1; acc += a2; acc += a3;
        }
        for (; j < m; ++j) {
            int r = __shfl(rj, j);
            acc += hs[(long)r * 64 + lane];
        }
    }
    out[(long)node * 64 + lane] = fmaxf(acc * dinv[node] + b[lane], 0.0f);
}

// ==================== edge scores via CSR ====================
// wave handles one node c; 4 edges in flight (16 lanes each, float4)
__global__ void k_edge_scores_csr(const int* __restrict__ start, const int* __restrict__ srow,
                                  const int* __restrict__ eid, const float* __restrict__ nr,
                                  float* __restrict__ out, int n) {
    int node = blockIdx.x * 4 + (threadIdx.x >> 6);
    if (node >= n) return;
    int lane = threadIdx.x & 63;
    int sub = lane & 15;   // channel group (4 ch each)
    int eg  = lane >> 4;   // which of 4 concurrent edges
    float4 c4 = *reinterpret_cast<const float4*>(&nr[(long)node * 64 + sub * 4]);
    int s = start[node], e2 = start[node + 1];
    for (int j = s + eg; j < e2; j += 4) {
        int r = srow[j];
        float4 a = *reinterpret_cast<const float4*>(&nr[(long)r * 64 + sub * 4]);
        float v = a.x * c4.x + a.y * c4.y + a.z * c4.z + a.w * c4.w;
        v += __shfl_xor(v, 1);
        v += __shfl_xor(v, 2);
        v += __shfl_xor(v, 4);
        v += __shfl_xor(v, 8);
        if (sub == 0) out[eid[j]] = v;
    }
}

// ==================== fallback path (small ws): atomic scatter ====================
__global__ void k_scatter_simple(const int* __restrict__ row, const int* __restrict__ col,
                                 const float* __restrict__ hs, float* __restrict__ acc, int e) {
    int t = blockIdx.x * blockDim.x + threadIdx.x;
    int lane = t & 63;
    int eidx = t >> 6;
    if (eidx >= e) return;
    int r = row[eidx], c = col[eidx];
    atomicAdd(&acc[(long)c * 64 + lane], hs[(long)r * 64 + lane]);
}
__global__ void k_epilogue2(float* __restrict__ acc, const float* __restrict__ hs,
                            const float* __restrict__ dinv, const float* __restrict__ b, int n) {
    int i = blockIdx.x * blockDim.x + threadIdx.x;
    if (i >= n * 64) return;
    int node = i >> 6, ch = i & 63;
    acc[i] = fmaxf(dinv[node] * (acc[i] + hs[i]) + b[ch], 0.0f);
}
__global__ void k_edge_scores_orig(const int* __restrict__ row, const int* __restrict__ col,
                                   const float* __restrict__ nr, float* __restrict__ out, int e) {
    int t = blockIdx.x * blockDim.x + threadIdx.x;
    int sub = t & 15;
    int eidx = t >> 4;
    if (eidx >= e) return;
    int r = row[eidx], c = col[eidx];
    float4 a  = *reinterpret_cast<const float4*>(&nr[(long)r * 64 + sub * 4]);
    float4 bb = *reinterpret_cast<const float4*>(&nr[(long)c * 64 + sub * 4]);
    float s = a.x * bb.x + a.y * bb.y + a.z * bb.z + a.w * bb.w;
    s += __shfl_xor(s, 1);
    s += __shfl_xor(s, 2);
    s += __shfl_xor(s, 4);
    s += __shfl_xor(s, 8);
    if (sub == 0) out[eidx] = s;
}

extern "C" void kernel_launch(void* const* d_in, const int* in_sizes, int n_in,
                              void* d_out, int out_size, void* d_ws, size_t ws_size,
                              hipStream_t stream) {
    const float* x   = (const float*)d_in[0];
    const int*   ei  = (const int*)d_in[1];
    const float* W1  = (const float*)d_in[2];
    const float* b1  = (const float*)d_in[3];
    const float* W2  = (const float*)d_in[4];
    const float* b2  = (const float*)d_in[5];
    const float* Wd1 = (const float*)d_in[6];
    const float* bd1 = (const float*)d_in[7];
    const float* Wd2 = (const float*)d_in[8];
    const float* bd2 = (const float*)d_in[9];

    const int N = in_sizes[0] / 128;
    const int E = in_sizes[1] / 2;
    const int* row = ei;
    const int* col = ei + E;
    const int n64 = N * 64;
    const int nb = (N + 1023) / 1024;

    // d_out layout: recon_x [N*128] | edge_scores [E] | node_repr [N*64]
    float* recon_out  = (float*)d_out;
    float* escore_out = recon_out + (long)N * 128;
    float* nr_out     = escore_out + E;

    // workspace layout
    float* dinv = (float*)d_ws;            // N
    float* buf1 = dinv + N;                // N*64
    float* buf2 = buf1 + (long)N * 64;     // N*64
    int* cnt    = (int*)(buf2 + (long)N * 64);  // N
    int* startp = cnt + N;                 // N+1
    int* cursor = startp + N + 1;          // N
    int* bsum   = cursor + N;              // pad 128
    int* srow   = bsum + 128;              // E
    int* eidp   = srow + E;                // E

    size_t need_full = sizeof(float) * ((size_t)N + 2uL * n64)
                     + sizeof(int) * (3uL * N + 1 + 128 + 2uL * E);

    if (ws_size >= need_full) {
        // ---------- CSR path (no fp atomics) ----------
        k_zero_i<<<(N + 255) / 256, 256, 0, stream>>>(cnt, N);
        k_deg_count<<<(E + 255) / 256, 256, 0, stream>>>(col, cnt, E);
        k_dinv<<<(N + 255) / 256, 256, 0, stream>>>(cnt, dinv, N);
        k_scan1<<<nb, 256, 0, stream>>>(cnt, startp, bsum, N);
        k_scan2<<<1, 64, 0, stream>>>(bsum, nb);
        k_scan3<<<(N + 255) / 256, 256, 0, stream>>>(startp, bsum, cursor, N, E);
        k_fill<<<(E + 255) / 256, 256, 0, stream>>>(row, col, cursor, srow, eidp, E);

        // layer 1: hs1 = (x@W1)*dinv  -> gather -> buf2 = relu(conv1)
        k_gemm<128, 64, false, false, true><<<(N + 15) / 16, 256, 0, stream>>>(x, W1, nullptr, dinv, buf1, N);
        k_gather_conv<<<(N + 3) / 4, 256, 0, stream>>>(startp, srow, buf1, dinv, b1, buf2, N);
        // layer 2: hs2 = (buf2@W2)*dinv -> gather -> nr
        k_gemm<64, 64, false, false, true><<<(N + 15) / 16, 256, 0, stream>>>(buf2, W2, nullptr, dinv, buf1, N);
        k_gather_conv<<<(N + 3) / 4, 256, 0, stream>>>(startp, srow, buf1, dinv, b2, nr_out, N);
        // decoder
        k_gemm<64, 64, true, true, false><<<(N + 15) / 16, 256, 0, stream>>>(nr_out, Wd1, bd1, nullptr, buf2, N);
        k_gemm<64, 128, true, false, false><<<(N + 7) / 8, 256, 0, stream>>>(buf2, Wd2, bd2, nullptr, recon_out, N);
        // edge scores via CSR
        k_edge_scores_csr<<<(N + 3) / 4, 256, 0, stream>>>(startp, srow, eidp, nr_out, escore_out, N);
    } else {
        // ---------- fallback: atomic scatter ----------
        k_zero_i<<<(N + 255) / 256, 256, 0, stream>>>(cnt, N);
        k_deg_count<<<(E + 255) / 256, 256, 0, stream>>>(col, cnt, E);
        k_dinv<<<(N + 255) / 256, 256, 0, stream>>>(cnt, dinv, N);
        k_zero_f<<<(n64 + 255) / 256, 256, 0, stream>>>(buf2, n64);
        k_zero_f<<<(n64 + 255) / 256, 256, 0, stream>>>(nr_out, n64);

        k_gemm<128, 64, false, false, true><<<(N + 15) / 16, 256, 0, stream>>>(x, W1, nullptr, dinv, buf1, N);
        k_scatter_simple<<<((long)E * 64 + 255) / 256, 256, 0, stream>>>(row, col, buf1, buf2, E);
        k_epilogue2<<<(n64 + 255) / 256, 256, 0, stream>>>(buf2, buf1, dinv, b1, N);
        k_gemm<64, 64, false, false, true><<<(N + 15) / 16, 256, 0, stream>>>(buf2, W2, nullptr, dinv, buf1, N);
        k_scatter_simple<<<((long)E * 64 + 255) / 256, 256, 0, stream>>>(row, col, buf1, nr_out, E);
        k_epilogue2<<<(n64 + 255) / 256, 256, 0, stream>>>(nr_out, buf1, dinv, b2, N);
        k_gemm<64, 64, true, true, false><<<(N + 15) / 16, 256, 0, stream>>>(nr_out, Wd1, bd1, nullptr, buf2, N);
        k_gemm<64, 128, true, false, false><<<(N + 7) / 8, 256, 0, stream>>>(buf2, Wd2, bd2, nullptr, recon_out, N);
        k_edge_scores_orig<<<((long)E * 16 + 255) / 256, 256, 0, stream>>>(row, col, nr_out, escore_out, E);
    }
}